// Round 15
// baseline (113.101 us; speedup 1.0000x reference)
//
#include <hip/hip_runtime.h>
#include <math.h>

// Problem constants (match reference)
constexpr int TPC    = 8;       // TP
constexpr int NNODES = 100000;
constexpr int BATCH  = 128;
constexpr int DMAX   = 64;
constexpr int Hc     = 15;
constexpr int Kc     = 15;
constexpr int NCAND  = Hc * Kc + 1;     // 226
constexpr int NLOCF  = NNODES * TPC;    // 800000

// lut[x] = f32 floor(log2(x))+1. At x=2^k a 1-ulp-low log2 can make the entry
// k instead of k+1, so the 16 entries at x in {0,1,2,4,...,2^14} come from the
// REAL lut input (powlut); everything else is 32-__clz(x). (R7+ pass, absmax 0.)
//
// R15: (a) 512-thread blocks; step 3 splits pos/neg tables across the two
// half-blocks (same per-accumulator d=0..63 order -> bit-identical numerics),
// doubling occupancy to 32 waves/CU and halving the serial LDS chain;
// (b) finish fused via two-level last-block-done counters (32-way spread;
// R9 showed same-address RMWs serialize ~9ns each) -> one launch total.

__launch_bounds__(512)
__global__ void main_kernel(const float* __restrict__ lut,
                            const int* __restrict__ sta_ind,
                            const int* __restrict__ locations,
                            const int* __restrict__ degree,
                            const int* __restrict__ pos_ind,
                            const int* __restrict__ neg_ind,
                            const int* __restrict__ rmasks,
                            const int* __restrict__ perm,
                            float* __restrict__ wsf,
                            int*   __restrict__ wsi,
                            unsigned* __restrict__ counters,
                            float* __restrict__ out) {
    // Table layout: T[d][g], g in [0,16) = term at bit-length g (non-pow2);
    // T[d][16+r] = term at bit-length powlut[r] (pow2 path).
    __shared__ float Tp[64][32];
    __shared__ float Tn[64][32];
    __shared__ int   ploc[64], nloc[64];
    __shared__ int   Sarr[2][64];
    __shared__ float Lsq[2][64];
    __shared__ float logLsq[64];
    __shared__ int   dsarr[2][64];
    __shared__ int   varr[2][64];
    __shared__ int   sh_sta[8];
    __shared__ int   powlut[16];
    __shared__ float lg_sh;
    __shared__ float part[512];           // ps (tid<256) / ns (tid>=256)
    __shared__ int   cval_sh[256];
    __shared__ float wmin[4];
    __shared__ int   widx[4];
    __shared__ int   lastflag;
    __shared__ float wsum[3][4];

    const int bid = blockIdx.x;
    const int b   = bid >> 3;
    const int t   = bid & 7;
    const int tid = threadIdx.x;
    const int sta = sta_ind[b];

    if (tid == 0) lastflag = 0;

    // Fused locations -> out[3..] copy (grid-stride slice).
    for (int idx = bid * 512 + tid; idx < NLOCF; idx += 1024 * 512)
        out[3 + idx] = (float)locations[idx];

    if (tid < 8) sh_sta[tid] = locations[sta * 8 + tid];
    if (tid >= 16 && tid < 32) {
        const int i = tid - 16;
        powlut[i] = (i == 0) ? (int)lut[0] : (int)lut[1 << (i - 1)];
    }
    __syncthreads();

    // ---- step 1: per-d quantities (threads 0..63 pos, 64..127 neg) ----
    if (tid < 128) {
        const int which = tid >> 6;
        const int d     = tid & 63;
        const int* ind  = which ? neg_ind : pos_ind;
        const int pi    = ind[b * DMAX + d];
        const int valid = (pi >= 0) ? 1 : 0;
        const int piw   = valid ? pi : pi + NNODES;   // -1 -> NNODES-1
        const int deg1  = degree[sta];
        const int deg2  = degree[piw];
        const float L   = logf((float)((deg1 + 1) * (deg2 + 1)));
        int Si = 0, dsi = 0, lc = 0;          // lc=0 if invalid (row g-constant)
        if (valid) {
            const int4* lp = reinterpret_cast<const int4*>(locations + pi * 8);
            const int4 va = lp[0], vb = lp[1];
            const int l0[8] = {va.x, va.y, va.z, va.w, vb.x, vb.y, vb.z, vb.w};
            #pragma unroll
            for (int tt = 0; tt < 8; ++tt) {
                const int x   = sh_sta[tt] ^ l0[tt];
                const int idx = 32 - __clz(x);
                const int bl  = ((x & (x - 1)) == 0) ? powlut[idx] : idx;
                Si += bl;
                if (tt == t) { dsi = bl; lc = l0[tt]; }
            }
        }
        const float lsq = L * L;
        Sarr[which][d]  = Si;
        Lsq[which][d]   = lsq;
        if (which == 0) logLsq[d] = logf(lsq);
        dsarr[which][d] = dsi;
        varr[which][d]  = valid;
        if (which == 0) ploc[d] = lc; else nloc[d] = lc;
        if (which == 0) {
            unsigned long long m = __ballot(valid);
            if (tid == 0) lg_sh = (float)__popcll(m);
        }
    }
    __syncthreads();

    // ---- step 2: fill all 32 entries per (which,d); 8 per thread ----
    // -log(p)     = logf(L^2 + y^2) - logf(L^2)
    // -log(1.1-p) = logf(L^2 + y^2) - logf(0.1*L^2 + 1.1*y^2),  y = x + 0.1
    for (int e = tid; e < 4096; e += 512) {
        const int which = e >> 11;
        const int rem   = e & 2047;
        const int d     = rem >> 5;
        const int slot  = rem & 31;
        const int g     = (slot < 16) ? slot : powlut[slot - 16];
        const float lsq = Lsq[which][d];
        float x;
        if (varr[which][d])
            x = (float)(g - dsarr[which][d] + Sarr[which][d]) * 0.125f;
        else
            x = which ? 1000.0f : 0.0f;   // reference fill values
        const float y  = x + 0.1f;
        const float s  = lsq + y * y;
        const float ls = logf(s);
        float term;
        if (which) term = ls - logf(0.1f * lsq + 1.1f * y * y);
        else       term = ls - logLsq[d];
        if (which) Tn[d][slot] = term; else Tp[d][slot] = term;
    }
    __syncthreads();

    // ---- step 3: half-block per table; same candidate on tid and tid+256 ----
    const int half = tid >> 8;            // 0 = pos table, 1 = neg table
    const int c    = tid & 255;
    float acc = 0.0f;
    int cval = 0;
    if (c < NCAND) {
        const int q  = perm[c];
        const int st = sh_sta[t];
        if (q < NCAND - 1) {
            const int h = q / Kc, k = q % Kc;
            cval = st ^ (1 << h) ^ rmasks[((b * Hc + h) * Kc + k) * 8 + t];
        } else {
            cval = st;
        }
        if (half == 0) {
            #pragma unroll 8
            for (int d = 0; d < 64; ++d) {              // strict d order (as R14)
                const int xp = cval ^ ploc[d];
                const int bp = 32 - __clz(xp);
                acc += Tp[d][((xp & (xp - 1)) == 0) ? bp + 16 : bp];
            }
            cval_sh[c] = cval;
        } else {
            #pragma unroll 8
            for (int d = 0; d < 64; ++d) {
                const int xn = cval ^ nloc[d];
                const int bn = 32 - __clz(xn);
                acc += Tn[d][((xn & (xn - 1)) == 0) ? bn + 16 : bn];
            }
        }
    }
    part[tid] = acc;
    __syncthreads();

    // ---- step 4: argmin over candidates (threads 0..255; first-index ties) ----
    float v = __builtin_inff();
    if (tid < 256 && c < NCAND) {
        const float lg = lg_sh;
        v = part[tid] / lg + part[tid + 256] / lg;    // plc + nlc, as before
    }
    int idx = tid & 255;
    #pragma unroll
    for (int m = 32; m >= 1; m >>= 1) {
        const float ov = __shfl_xor(v, m, 64);
        const int   oi = __shfl_xor(idx, m, 64);
        if (ov < v || (ov == v && oi < idx)) { v = ov; idx = oi; }
    }
    if (tid < 256 && (tid & 63) == 0) { wmin[tid >> 6] = v; widx[tid >> 6] = idx; }
    __syncthreads();

    if (tid == 0) {
        float bv = wmin[0];
        int   bi = widx[0];
        #pragma unroll
        for (int w = 1; w < 4; ++w) {
            const float vv = wmin[w];
            const int   ii = widx[w];
            if (vv < bv || (vv == bv && ii < bi)) { bv = vv; bi = ii; }
        }
        const float lg = lg_sh;
        wsf[bid]        = bv;
        wsf[1024 + bid] = part[bi] / lg;          // pos_loss of winner
        wsf[2048 + bid] = part[256 + bi] / lg;    // neg_loss of winner
        wsi[bid]        = cval_sh[bi];
        __threadfence();
        // Two-level completion counters (avoid 1024 same-address RMWs, cf. R9).
        const unsigned g1 = atomicAdd(&counters[bid & 31], 1u);
        if (g1 == 31) {                            // last of this 32-block group
            const unsigned g2 = atomicAdd(&counters[32], 1u);
            if (g2 == 31) lastflag = 1;            // last group overall
        }
    }
    __syncthreads();

    // ---- finish (runs in exactly one block, after all slots are written) ----
    if (lastflag) {
        __threadfence();                           // acquire: see other blocks' slots
        if (tid < 256) {
            #pragma unroll
            for (int a = 0; a < 3; ++a) {
                float s = 0.0f;
                #pragma unroll
                for (int j = 0; j < 4; ++j) s += wsf[a * 1024 + j * 256 + tid];
                #pragma unroll
                for (int m = 32; m >= 1; m >>= 1) s += __shfl_xor(s, m, 64);
                if ((tid & 63) == 0) wsum[a][tid >> 6] = s;
            }
            // Scatter the 1024 selected location components.
            #pragma unroll
            for (int j = 0; j < 4; ++j) {
                const int i  = j * 256 + tid;      // (b,t) flat index
                const int bb = i >> 3, tt = i & 7;
                out[3 + sta_ind[bb] * 8 + tt] = (float)wsi[i];
            }
        }
        __syncthreads();
        if (tid < 3)
            out[tid] = (wsum[tid][0] + wsum[tid][1] + wsum[tid][2] + wsum[tid][3])
                       * (1.0f / 1024.0f);
    }
}

extern "C" void kernel_launch(void* const* d_in, const int* in_sizes, int n_in,
                              void* d_out, int out_size, void* d_ws, size_t ws_size,
                              hipStream_t stream) {
    // setup_inputs order: lut, sta_ind, locations, degree, pos_ind, neg_ind, random_masks, perm
    const float* lut     = (const float*)d_in[0];
    const int* sta_ind   = (const int*)d_in[1];
    const int* locations = (const int*)d_in[2];
    const int* degree    = (const int*)d_in[3];
    const int* pos_ind   = (const int*)d_in[4];
    const int* neg_ind   = (const int*)d_in[5];
    const int* rmasks    = (const int*)d_in[6];
    const int* perm      = (const int*)d_in[7];
    float* out = (float*)d_out;
    float*    wsf      = (float*)d_ws;                          // 3072 floats
    int*      wsi      = (int*)((char*)d_ws + 12288);           // 1024 ints
    unsigned* counters = (unsigned*)((char*)d_ws + 16384);      // 33 uints

    hipMemsetAsync(counters, 0, 33 * sizeof(unsigned), stream); // zero-init (ws is 0xAA-poisoned)
    hipLaunchKernelGGL(main_kernel, dim3(BATCH * TPC), dim3(512), 0, stream,
                       lut, sta_ind, locations, degree, pos_ind, neg_ind, rmasks, perm,
                       wsf, wsi, counters, out);
}